// Round 5
// baseline (260.191 us; speedup 1.0000x reference)
//
#include <hip/hip_runtime.h>
#include <cfloat>
#include <math.h>

#define N_OBJ 8
#define N_PTS 2048
#define KNN   10
#define TOLC  0.01f
#define TPB   256
#define NW    4                 // waves per block = q-split factor
#define QC    (N_PTS / NW)      // 512 q's per wave
#define PC    64                // points per block (one wave-width)
#define NCHUNK (N_PTS / PC)     // 32 point-chunks per pair

// ---- order-preserving float <-> uint for atomicMin on signed floats ----
__device__ __forceinline__ unsigned int enc_f(float f) {
    unsigned int u = __float_as_uint(f);
    return (u & 0x80000000u) ? ~u : (u | 0x80000000u);
}
__device__ __forceinline__ float dec_f(unsigned int e) {
    unsigned int u = (e & 0x80000000u) ? (e & 0x7fffffffu) : ~e;
    return __uint_as_float(u);
}

// Kernel 1: per-point transform (4x4 inverse redundantly in double — closer
// to the numpy reference than fp32 adjugate; trivial cost at 64 waves).
// Writes P4=(x,y,z,|x|^2), N4=(nx,ny,nz,dot(n,x)), SD seed = enc(z).
__global__ void k_transform(const float* __restrict__ pts,
                            const float* __restrict__ T_est,
                            const float* __restrict__ T_plane,
                            float4* __restrict__ P4g,
                            float4* __restrict__ N4g,
                            unsigned int* __restrict__ SD) {
    int gid = blockIdx.x * blockDim.x + threadIdx.x;
    if (gid >= N_OBJ * N_PTS) return;
    int b = gid >> 11;

    double m[16];
#pragma unroll
    for (int i = 0; i < 16; i++) m[i] = (double)T_plane[i];
    double inv[16];
    inv[0]  =  m[5]*m[10]*m[15] - m[5]*m[11]*m[14] - m[9]*m[6]*m[15] + m[9]*m[7]*m[14] + m[13]*m[6]*m[11] - m[13]*m[7]*m[10];
    inv[4]  = -m[4]*m[10]*m[15] + m[4]*m[11]*m[14] + m[8]*m[6]*m[15] - m[8]*m[7]*m[14] - m[12]*m[6]*m[11] + m[12]*m[7]*m[10];
    inv[8]  =  m[4]*m[9]*m[15]  - m[4]*m[11]*m[13] - m[8]*m[5]*m[15] + m[8]*m[7]*m[13] + m[12]*m[5]*m[11] - m[12]*m[7]*m[9];
    inv[12] = -m[4]*m[9]*m[14]  + m[4]*m[10]*m[13] + m[8]*m[5]*m[14] - m[8]*m[6]*m[13] - m[12]*m[5]*m[10] + m[12]*m[6]*m[9];
    inv[1]  = -m[1]*m[10]*m[15] + m[1]*m[11]*m[14] + m[9]*m[2]*m[15] - m[9]*m[3]*m[14] - m[13]*m[2]*m[11] + m[13]*m[3]*m[10];
    inv[5]  =  m[0]*m[10]*m[15] - m[0]*m[11]*m[14] - m[8]*m[2]*m[15] + m[8]*m[3]*m[14] + m[12]*m[2]*m[11] - m[12]*m[3]*m[10];
    inv[9]  = -m[0]*m[9]*m[15]  + m[0]*m[11]*m[13] + m[8]*m[1]*m[15] - m[8]*m[3]*m[13] - m[12]*m[1]*m[11] + m[12]*m[3]*m[9];
    inv[13] =  m[0]*m[9]*m[14]  - m[0]*m[10]*m[13] - m[8]*m[1]*m[14] + m[8]*m[2]*m[13] + m[12]*m[1]*m[10] - m[12]*m[2]*m[9];
    inv[2]  =  m[1]*m[6]*m[15]  - m[1]*m[7]*m[14]  - m[5]*m[2]*m[15] + m[5]*m[3]*m[14] + m[13]*m[2]*m[7]  - m[13]*m[3]*m[6];
    inv[6]  = -m[0]*m[6]*m[15]  + m[0]*m[7]*m[14]  + m[4]*m[2]*m[15] - m[4]*m[3]*m[14] - m[12]*m[2]*m[7]  + m[12]*m[3]*m[6];
    inv[10] =  m[0]*m[5]*m[15]  - m[0]*m[7]*m[13]  - m[4]*m[1]*m[15] + m[4]*m[3]*m[13] + m[12]*m[1]*m[7]  - m[12]*m[3]*m[5];
    inv[14] = -m[0]*m[5]*m[14]  + m[0]*m[6]*m[13]  + m[4]*m[1]*m[14] - m[4]*m[2]*m[13] - m[12]*m[1]*m[6]  + m[12]*m[2]*m[5];
    inv[3]  = -m[1]*m[6]*m[11]  + m[1]*m[7]*m[10]  + m[5]*m[2]*m[11] - m[5]*m[3]*m[10] - m[9]*m[2]*m[7]   + m[9]*m[3]*m[6];
    inv[7]  =  m[0]*m[6]*m[11]  - m[0]*m[7]*m[10]  - m[4]*m[2]*m[11] + m[4]*m[3]*m[10] + m[8]*m[2]*m[7]   - m[8]*m[3]*m[6];
    inv[11] = -m[0]*m[5]*m[11]  + m[0]*m[7]*m[9]   + m[4]*m[1]*m[11] - m[4]*m[3]*m[9]  - m[8]*m[1]*m[7]   + m[8]*m[3]*m[5];
    inv[15] =  m[0]*m[5]*m[10]  - m[0]*m[6]*m[9]   - m[4]*m[1]*m[10] + m[4]*m[2]*m[9]  + m[8]*m[1]*m[6]   - m[8]*m[2]*m[5];
    double det  = m[0]*inv[0] + m[1]*inv[4] + m[2]*inv[8] + m[3]*inv[12];
    double rdet = 1.0 / det;

    const float* Te = T_est + b * 16;
    double M[12];
#pragma unroll
    for (int i = 0; i < 3; i++)
#pragma unroll
        for (int j = 0; j < 4; j++) {
            double s = 0.0;
#pragma unroll
            for (int kk = 0; kk < 4; kk++) s += inv[i*4+kk] * rdet * (double)Te[kk*4+j];
            M[i*4+j] = s;
        }

    const float* pp = pts + (size_t)gid * 6;
    double px = pp[0], py = pp[1], pz = pp[2];
    float nx = pp[3], ny = pp[4], nz = pp[5];
    float x = (float)(M[0]*px + M[1]*py + M[2]*pz  + M[3]);
    float y = (float)(M[4]*px + M[5]*py + M[6]*pz  + M[7]);
    float z = (float)(M[8]*px + M[9]*py + M[10]*pz + M[11]);
    float sq = fmaf(x, x, fmaf(y, y, z * z));
    float w  = fmaf(nx, x, fmaf(ny, y, nz * z));
    P4g[gid] = make_float4(x, y, z, sq);
    N4g[gid] = make_float4(nx, ny, nz, w);
    SD[gid]  = enc_f(z);   // seed min with the plane-distance term z
}

// One candidate: 22 VALU ops exactly, bit-identical order to previous rounds.
#define QB(PX,PY,PZ,PW,NX,NY,NZ,NWW) \
  "v_mul_f32 %[t0], " PZ ", %[mz]\n" \
  "v_fma_f32 %[t0], %[my], " PY ", %[t0]\n" \
  "v_fma_f32 %[t0], %[mx], " PX ", %[t0]\n" \
  "v_add_f32 %[t0], " PW ", %[t0]\n" \
  "v_mul_f32 %[t1], " NZ ", %[gz]\n" \
  "v_fma_f32 %[t1], %[gy], " NY ", %[t1]\n" \
  "v_fma_f32 %[t1], %[gx], " NX ", %[t1]\n" \
  "v_add_f32 %[t1], " NWW ", %[t1]\n" \
  "v_and_b32 %[t0], -2, %[t0]\n" \
  "v_cmp_lt_f32 vcc, 0, %[t1]\n" \
  "v_cndmask_b32_e64 %[t1], 0, 1, vcc\n" \
  "v_or_b32 %[t0], %[t0], %[t1]\n" \
  "v_med3_f32 %[d9], %[d8], %[d9], %[t0]\n" \
  "v_med3_f32 %[d8], %[d7], %[d8], %[t0]\n" \
  "v_med3_f32 %[d7], %[d6], %[d7], %[t0]\n" \
  "v_med3_f32 %[d6], %[d5], %[d6], %[t0]\n" \
  "v_med3_f32 %[d5], %[d4], %[d5], %[t0]\n" \
  "v_med3_f32 %[d4], %[d3], %[d4], %[t0]\n" \
  "v_med3_f32 %[d3], %[d2], %[d3], %[t0]\n" \
  "v_med3_f32 %[d2], %[d1], %[d2], %[t0]\n" \
  "v_med3_f32 %[d1], %[d0], %[d1], %[t0]\n" \
  "v_min_f32 %[d0], %[d0], %[t0]\n"

// issue one slot's 8 loads (4 P + 4 N float4s) at byte offset OFF (string)
#define LDSLOT(P0,P1,P2,P3,Q0,Q1,Q2,Q3,O0,O1,O2,O3) \
  "global_load_dwordx4 " P0 ", %[vz], s[32:33] offset:" O0 "\n" \
  "global_load_dwordx4 " P1 ", %[vz], s[32:33] offset:" O1 "\n" \
  "global_load_dwordx4 " P2 ", %[vz], s[32:33] offset:" O2 "\n" \
  "global_load_dwordx4 " P3 ", %[vz], s[32:33] offset:" O3 "\n" \
  "global_load_dwordx4 " Q0 ", %[vz], s[34:35] offset:" O0 "\n" \
  "global_load_dwordx4 " Q1 ", %[vz], s[34:35] offset:" O1 "\n" \
  "global_load_dwordx4 " Q2 ", %[vz], s[34:35] offset:" O2 "\n" \
  "global_load_dwordx4 " Q3 ", %[vz], s[34:35] offset:" O3 "\n"

#define SLOT0_LD(O0,O1,O2,O3) LDSLOT("v[32:35]","v[36:39]","v[40:43]","v[44:47]", \
                                     "v[48:51]","v[52:55]","v[56:59]","v[60:63]",O0,O1,O2,O3)
#define SLOT1_LD(O0,O1,O2,O3) LDSLOT("v[64:67]","v[68:71]","v[72:75]","v[76:79]", \
                                     "v[80:83]","v[84:87]","v[88:91]","v[92:95]",O0,O1,O2,O3)
#define SLOT2_LD(O0,O1,O2,O3) LDSLOT("v[96:99]","v[100:103]","v[104:107]","v[108:111]", \
                                     "v[112:115]","v[116:119]","v[120:123]","v[124:127]",O0,O1,O2,O3)

#define SLOT0_QB \
  QB("v32","v33","v34","v35","v48","v49","v50","v51") \
  QB("v36","v37","v38","v39","v52","v53","v54","v55") \
  QB("v40","v41","v42","v43","v56","v57","v58","v59") \
  QB("v44","v45","v46","v47","v60","v61","v62","v63")
#define SLOT1_QB \
  QB("v64","v65","v66","v67","v80","v81","v82","v83") \
  QB("v68","v69","v70","v71","v84","v85","v86","v87") \
  QB("v72","v73","v74","v75","v88","v89","v90","v91") \
  QB("v76","v77","v78","v79","v92","v93","v94","v95")
#define SLOT2_QB \
  QB("v96","v97","v98","v99","v112","v113","v114","v115") \
  QB("v100","v101","v102","v103","v116","v117","v118","v119") \
  QB("v104","v105","v106","v107","v120","v121","v122","v123") \
  QB("v108","v109","v110","v111","v124","v125","v126","v127")

// Kernel 2 v5: both streams on VMEM with COUNTED vmcnt prefetch (vmcnt is
// in-order, unlike SMEM's lgkmcnt whose OOO completion pinned r4's prefetch
// distance to 176cy < ~300cy L2 latency = the measured 42% stall).
//   - 3 VGPR slots (v32..v127 hard-clobbered), each 4 q x (P f4x4 + N f4x4)
//   - wave-uniform global_load_dwordx4 (64 lanes same addr -> 1 L2 request,
//     broadcast); saddr advanced by SALU; vaddr = constant-0 VGPR -> zero
//     VALU address math
//   - rotation: issue slot k+2 (8 loads) -> s_waitcnt vmcnt(16) -> compute
//     slot k. Prefetch distance = 2 compute blocks ~= 352cy > latency.
//   - 128 groups = prologue(2) + 42 iters x 3 + epilogue(2); no overrun.
// Body is the same 22-VALU QB macro (bit-identical results).
__global__ void __launch_bounds__(TPB, 4) k_pairs(const float4* __restrict__ P4g,
                                                  const float4* __restrict__ N4g,
                                                  unsigned int* __restrict__ SD) {
    // stride 11 floats: 11 coprime 32 -> 2 lanes/bank, conflict-free
    __shared__ float MRG[NW][PC][KNN + 1];

    int bx   = blockIdx.x;
    int pair = bx >> 5;            // / NCHUNK
    int c64  = bx & (NCHUNK - 1);
    int b  = pair / 7;
    int oi = pair % 7;
    int o  = oi + (oi >= b ? 1 : 0);
    int tid  = threadIdx.x;
    int lane = tid & 63;
    int wu   = __builtin_amdgcn_readfirstlane(tid >> 6);
    int p    = c64 * PC + lane;

    float4 xp = P4g[b * N_PTS + p];          // per-lane point p (VMEM)
    float mx = -2.0f * xp.x, my = -2.0f * xp.y, mz = -2.0f * xp.z;
    float gx = -xp.x, gy = -xp.y, gz = -xp.z;

    const float4* Po = P4g + o * N_PTS + wu * QC;   // uniform stream bases
    const float4* No = N4g + o * N_PTS + wu * QC;
    unsigned long long ap = (unsigned long long)(uintptr_t)Po;
    unsigned long long an = (unsigned long long)(uintptr_t)No;
    unsigned int bpl = (unsigned int)ap, bph = (unsigned int)(ap >> 32);
    unsigned int bnl = (unsigned int)an, bnh = (unsigned int)(an >> 32);

    const float FMAXE = __uint_as_float(0x7F7FFFFEu);   // FLT_MAX, LSB clear
    float d0_ = FMAXE, d1_ = FMAXE, d2_ = FMAXE, d3_ = FMAXE, d4_ = FMAXE;
    float d5_ = FMAXE, d6_ = FMAXE, d7_ = FMAXE, d8_ = FMAXE, d9_ = FMAXE;
    float t0, t1;

    asm volatile(
        "s_mov_b32 s32, %[bpl]\n"
        "s_mov_b32 s33, %[bph]\n"
        "s_mov_b32 s34, %[bnl]\n"
        "s_mov_b32 s35, %[bnh]\n"
        // prologue: groups 0,1 into slots 0,1   (16 loads outstanding)
        SLOT0_LD("0","16","32","48")
        SLOT1_LD("64","80","96","112")
        "s_mov_b32 s30, 0\n"
        "Lkp%=:\n"
        // issue group g+2 -> slot2; wait slot0; compute slot0 (group g)
        SLOT2_LD("128","144","160","176")
        "s_waitcnt vmcnt(16)\n"
        SLOT0_QB
        // issue group g+3 -> slot0; wait slot1; compute slot1
        SLOT0_LD("192","208","224","240")
        "s_waitcnt vmcnt(16)\n"
        SLOT1_QB
        // issue group g+4 -> slot1; wait slot2; compute slot2
        SLOT1_LD("256","272","288","304")
        "s_waitcnt vmcnt(16)\n"
        SLOT2_QB
        "s_add_u32 s32, s32, 0xc0\n"
        "s_addc_u32 s33, s33, 0\n"
        "s_add_u32 s34, s34, 0xc0\n"
        "s_addc_u32 s35, s35, 0\n"
        "s_add_u32 s30, s30, 1\n"
        "s_cmp_lt_u32 s30, 42\n"
        "s_cbranch_scc1 Lkp%=\n"
        // epilogue: groups 126 (slot0), 127 (slot1) already in flight
        "s_waitcnt vmcnt(8)\n"
        SLOT0_QB
        "s_waitcnt vmcnt(0)\n"
        SLOT1_QB
        : [d0]"+v"(d0_), [d1]"+v"(d1_), [d2]"+v"(d2_), [d3]"+v"(d3_),
          [d4]"+v"(d4_), [d5]"+v"(d5_), [d6]"+v"(d6_), [d7]"+v"(d7_),
          [d8]"+v"(d8_), [d9]"+v"(d9_), [t0]"=&v"(t0), [t1]"=&v"(t1)
        : [mx]"v"(mx), [my]"v"(my), [mz]"v"(mz),
          [gx]"v"(gx), [gy]"v"(gy), [gz]"v"(gz),
          [vz]"v"(0),
          [bpl]"s"(bpl), [bph]"s"(bph), [bnl]"s"(bnl), [bnh]"s"(bnh)
        : "s30","s32","s33","s34","s35",
          "v32","v33","v34","v35","v36","v37","v38","v39",
          "v40","v41","v42","v43","v44","v45","v46","v47",
          "v48","v49","v50","v51","v52","v53","v54","v55",
          "v56","v57","v58","v59","v60","v61","v62","v63",
          "v64","v65","v66","v67","v68","v69","v70","v71",
          "v72","v73","v74","v75","v76","v77","v78","v79",
          "v80","v81","v82","v83","v84","v85","v86","v87",
          "v88","v89","v90","v91","v92","v93","v94","v95",
          "v96","v97","v98","v99","v100","v101","v102","v103",
          "v104","v105","v106","v107","v108","v109","v110","v111",
          "v112","v113","v114","v115","v116","v117","v118","v119",
          "v120","v121","v122","v123","v124","v125","v126","v127",
          "scc","vcc","memory");

    float td[KNN] = {d0_, d1_, d2_, d3_, d4_, d5_, d6_, d7_, d8_, d9_};

    if (wu > 0) {
#pragma unroll
        for (int j = 0; j < KNN; j++) MRG[wu][lane][j] = td[j];
    }
    __syncthreads();

    if (wu == 0) {
        // merge the 3 foreign partial top-10 lists into this wave's network
        // (top-k selection is partition-invariant on the value multiset)
#pragma unroll
        for (int ww = 1; ww < NW; ww++) {
#pragma unroll
            for (int j = 0; j < KNN; j++) {
                float cp = MRG[ww][lane][j];
#pragma unroll
                for (int t = KNN - 1; t >= 1; --t)
                    td[t] = __builtin_amdgcn_fmed3f(td[t - 1], td[t], cp);
                td[0] = fminf(td[0], cp);
            }
        }

        int cnt = 0;
#pragma unroll
        for (int j = 0; j < KNN; j++) cnt += (int)(__float_as_uint(td[j]) & 1u);
        float d2 = __uint_as_float(__float_as_uint(td[0]) & 0xFFFFFFFEu) + xp.w;
        float d0 = sqrtf(fmaxf(d2, 0.0f));
        if (cnt > 8) d0 = -d0;           // sum(insides) > k*0.8 = 8  ->  >= 9
        atomicMin(&SD[b * N_PTS + p], enc_f(d0));
    }
}

// Kernel 3: decode and emit both outputs (signed_distance, then intersects
// as 0.0/1.0 floats).
__global__ void k_final(const unsigned int* __restrict__ SD,
                       float* __restrict__ out) {
    int gid = blockIdx.x * blockDim.x + threadIdx.x;
    if (gid >= N_OBJ * N_PTS) return;
    float sd = dec_f(SD[gid]);
    out[gid] = sd;
    out[N_OBJ * N_PTS + gid] = (sd < -TOLC) ? 1.0f : 0.0f;
}

extern "C" void kernel_launch(void* const* d_in, const int* in_sizes, int n_in,
                              void* d_out, int out_size, void* d_ws, size_t ws_size,
                              hipStream_t stream) {
    const float* pts     = (const float*)d_in[0];   // (8,2048,6)
    const float* T_est   = (const float*)d_in[1];   // (8,4,4)
    const float* T_plane = (const float*)d_in[2];   // (4,4)
    // d_in[3] is k == 10, hardcoded as KNN

    // workspace layout: P4 (256KB) | N4 (256KB) | SD (64KB)
    float4*       P4 = (float4*)d_ws;
    float4*       N4 = P4 + N_OBJ * N_PTS;
    unsigned int* SD = (unsigned int*)(N4 + N_OBJ * N_PTS);

    float* out = (float*)d_out;

    k_transform<<<(N_OBJ * N_PTS) / 256, 256, 0, stream>>>(pts, T_est, T_plane, P4, N4, SD);
    k_pairs<<<N_OBJ * (N_OBJ - 1) * NCHUNK, TPB, 0, stream>>>(P4, N4, SD);
    k_final<<<(N_OBJ * N_PTS) / 256, 256, 0, stream>>>(SD, out);
}

// Round 6
// 164.932 us; speedup vs baseline: 1.5776x; 1.5776x over previous
//
#include <hip/hip_runtime.h>
#include <cfloat>
#include <math.h>

#define N_OBJ 8
#define N_PTS 2048
#define KNN   10
#define TOLC  0.01f
#define TPB   256
#define NW    4                 // waves per block = q-split factor
#define QC    (N_PTS / NW)      // 512 q's per wave
#define PC    64                // points per block (one wave-width)
#define NCHUNK (N_PTS / PC)     // 32 point-chunks per pair

// ---- order-preserving float <-> uint for atomicMin on signed floats ----
__device__ __forceinline__ unsigned int enc_f(float f) {
    unsigned int u = __float_as_uint(f);
    return (u & 0x80000000u) ? ~u : (u | 0x80000000u);
}
__device__ __forceinline__ float dec_f(unsigned int e) {
    unsigned int u = (e & 0x80000000u) ? (e & 0x7fffffffu) : ~e;
    return __uint_as_float(u);
}

// Kernel 1: per-point transform (4x4 inverse redundantly in double — closer
// to the numpy reference than fp32 adjugate; trivial cost at 64 waves).
// Writes P4=(x,y,z,|x|^2), N4=(nx,ny,nz,dot(n,x)), SD seed = enc(z).
__global__ void k_transform(const float* __restrict__ pts,
                            const float* __restrict__ T_est,
                            const float* __restrict__ T_plane,
                            float4* __restrict__ P4g,
                            float4* __restrict__ N4g,
                            unsigned int* __restrict__ SD) {
    int gid = blockIdx.x * blockDim.x + threadIdx.x;
    if (gid >= N_OBJ * N_PTS) return;
    int b = gid >> 11;

    double m[16];
#pragma unroll
    for (int i = 0; i < 16; i++) m[i] = (double)T_plane[i];
    double inv[16];
    inv[0]  =  m[5]*m[10]*m[15] - m[5]*m[11]*m[14] - m[9]*m[6]*m[15] + m[9]*m[7]*m[14] + m[13]*m[6]*m[11] - m[13]*m[7]*m[10];
    inv[4]  = -m[4]*m[10]*m[15] + m[4]*m[11]*m[14] + m[8]*m[6]*m[15] - m[8]*m[7]*m[14] - m[12]*m[6]*m[11] + m[12]*m[7]*m[10];
    inv[8]  =  m[4]*m[9]*m[15]  - m[4]*m[11]*m[13] - m[8]*m[5]*m[15] + m[8]*m[7]*m[13] + m[12]*m[5]*m[11] - m[12]*m[7]*m[9];
    inv[12] = -m[4]*m[9]*m[14]  + m[4]*m[10]*m[13] + m[8]*m[5]*m[14] - m[8]*m[6]*m[13] - m[12]*m[5]*m[10] + m[12]*m[6]*m[9];
    inv[1]  = -m[1]*m[10]*m[15] + m[1]*m[11]*m[14] + m[9]*m[2]*m[15] - m[9]*m[3]*m[14] - m[13]*m[2]*m[11] + m[13]*m[3]*m[10];
    inv[5]  =  m[0]*m[10]*m[15] - m[0]*m[11]*m[14] - m[8]*m[2]*m[15] + m[8]*m[3]*m[14] + m[12]*m[2]*m[11] - m[12]*m[3]*m[10];
    inv[9]  = -m[0]*m[9]*m[15]  + m[0]*m[11]*m[13] + m[8]*m[1]*m[15] - m[8]*m[3]*m[13] - m[12]*m[1]*m[11] + m[12]*m[3]*m[9];
    inv[13] =  m[0]*m[9]*m[14]  - m[0]*m[10]*m[13] - m[8]*m[1]*m[14] + m[8]*m[2]*m[13] + m[12]*m[1]*m[10] - m[12]*m[2]*m[9];
    inv[2]  =  m[1]*m[6]*m[15]  - m[1]*m[7]*m[14]  - m[5]*m[2]*m[15] + m[5]*m[3]*m[14] + m[13]*m[2]*m[7]  - m[13]*m[3]*m[6];
    inv[6]  = -m[0]*m[6]*m[15]  + m[0]*m[7]*m[14]  + m[4]*m[2]*m[15] - m[4]*m[3]*m[14] - m[12]*m[2]*m[7]  + m[12]*m[3]*m[6];
    inv[10] =  m[0]*m[5]*m[15]  - m[0]*m[7]*m[13]  - m[4]*m[1]*m[15] + m[4]*m[3]*m[13] + m[12]*m[1]*m[7]  - m[12]*m[3]*m[5];
    inv[14] = -m[0]*m[5]*m[14]  + m[0]*m[6]*m[13]  + m[4]*m[1]*m[14] - m[4]*m[2]*m[13] - m[12]*m[1]*m[6]  + m[12]*m[2]*m[5];
    inv[3]  = -m[1]*m[6]*m[11]  + m[1]*m[7]*m[10]  + m[5]*m[2]*m[11] - m[5]*m[3]*m[10] - m[9]*m[2]*m[7]   + m[9]*m[3]*m[6];
    inv[7]  =  m[0]*m[6]*m[11]  - m[0]*m[7]*m[10]  - m[4]*m[2]*m[11] + m[4]*m[3]*m[10] + m[8]*m[2]*m[7]   - m[8]*m[3]*m[6];
    inv[11] = -m[0]*m[5]*m[11]  + m[0]*m[7]*m[9]   + m[4]*m[1]*m[11] - m[4]*m[3]*m[9]  - m[8]*m[1]*m[7]   + m[8]*m[3]*m[5];
    inv[15] =  m[0]*m[5]*m[10]  - m[0]*m[6]*m[9]   - m[4]*m[1]*m[10] + m[4]*m[2]*m[9]  + m[8]*m[1]*m[6]   - m[8]*m[2]*m[5];
    double det  = m[0]*inv[0] + m[1]*inv[4] + m[2]*inv[8] + m[3]*inv[12];
    double rdet = 1.0 / det;

    const float* Te = T_est + b * 16;
    double M[12];
#pragma unroll
    for (int i = 0; i < 3; i++)
#pragma unroll
        for (int j = 0; j < 4; j++) {
            double s = 0.0;
#pragma unroll
            for (int kk = 0; kk < 4; kk++) s += inv[i*4+kk] * rdet * (double)Te[kk*4+j];
            M[i*4+j] = s;
        }

    const float* pp = pts + (size_t)gid * 6;
    double px = pp[0], py = pp[1], pz = pp[2];
    float nx = pp[3], ny = pp[4], nz = pp[5];
    float x = (float)(M[0]*px + M[1]*py + M[2]*pz  + M[3]);
    float y = (float)(M[4]*px + M[5]*py + M[6]*pz  + M[7]);
    float z = (float)(M[8]*px + M[9]*py + M[10]*pz + M[11]);
    float sq = fmaf(x, x, fmaf(y, y, z * z));
    float w  = fmaf(nx, x, fmaf(ny, y, nz * z));
    P4g[gid] = make_float4(x, y, z, sq);
    N4g[gid] = make_float4(nx, ny, nz, w);
    SD[gid]  = enc_f(z);   // seed min with the plane-distance term z
}

// One candidate: 22 VALU ops, bit-identical order to rounds 0-5.
// P operands are VGPRs (from ds_read), N operands are SGPRs (from s_load);
// every VALU inst reads <=1 SGPR (SGPR in src0 for VOP2, src1 for VOP3 fma).
#define QB(PX,PY,PZ,PW,NX,NY,NZ,NWW) \
  "v_mul_f32 %[t0], " PZ ", %[mz]\n" \
  "v_fma_f32 %[t0], %[my], " PY ", %[t0]\n" \
  "v_fma_f32 %[t0], %[mx], " PX ", %[t0]\n" \
  "v_add_f32 %[t0], " PW ", %[t0]\n" \
  "v_mul_f32 %[t1], " NZ ", %[gz]\n" \
  "v_fma_f32 %[t1], %[gy], " NY ", %[t1]\n" \
  "v_fma_f32 %[t1], %[gx], " NX ", %[t1]\n" \
  "v_add_f32 %[t1], " NWW ", %[t1]\n" \
  "v_and_b32 %[t0], -2, %[t0]\n" \
  "v_cmp_lt_f32 vcc, 0, %[t1]\n" \
  "v_cndmask_b32_e64 %[t1], 0, 1, vcc\n" \
  "v_or_b32 %[t0], %[t0], %[t1]\n" \
  "v_med3_f32 %[d9], %[d8], %[d9], %[t0]\n" \
  "v_med3_f32 %[d8], %[d7], %[d8], %[t0]\n" \
  "v_med3_f32 %[d7], %[d6], %[d7], %[t0]\n" \
  "v_med3_f32 %[d6], %[d5], %[d6], %[t0]\n" \
  "v_med3_f32 %[d5], %[d4], %[d5], %[t0]\n" \
  "v_med3_f32 %[d4], %[d3], %[d4], %[t0]\n" \
  "v_med3_f32 %[d3], %[d2], %[d3], %[t0]\n" \
  "v_med3_f32 %[d2], %[d1], %[d2], %[t0]\n" \
  "v_med3_f32 %[d1], %[d0], %[d1], %[t0]\n" \
  "v_min_f32 %[d0], %[d0], %[t0]\n"

// 8 uniform ds_read_b128 (one 8-q group of P) at byte offsets O0..O7 from %[lb]
#define DS8(V0,V1,V2,V3,V4,V5,V6,V7,O0,O1,O2,O3,O4,O5,O6,O7) \
  "ds_read_b128 " V0 ", %[lb] offset:" O0 "\n" \
  "ds_read_b128 " V1 ", %[lb] offset:" O1 "\n" \
  "ds_read_b128 " V2 ", %[lb] offset:" O2 "\n" \
  "ds_read_b128 " V3 ", %[lb] offset:" O3 "\n" \
  "ds_read_b128 " V4 ", %[lb] offset:" O4 "\n" \
  "ds_read_b128 " V5 ", %[lb] offset:" O5 "\n" \
  "ds_read_b128 " V6 ", %[lb] offset:" O6 "\n" \
  "ds_read_b128 " V7 ", %[lb] offset:" O7 "\n"

#define DSA(O0,O1,O2,O3,O4,O5,O6,O7) \
  DS8("v[32:35]","v[36:39]","v[40:43]","v[44:47]", \
      "v[48:51]","v[52:55]","v[56:59]","v[60:63]",O0,O1,O2,O3,O4,O5,O6,O7)
#define DSB(O0,O1,O2,O3,O4,O5,O6,O7) \
  DS8("v[64:67]","v[68:71]","v[72:75]","v[76:79]", \
      "v[80:83]","v[84:87]","v[88:91]","v[92:95]",O0,O1,O2,O3,O4,O5,O6,O7)

#define QB_A \
  QB("v32","v33","v34","v35","s36","s37","s38","s39") \
  QB("v36","v37","v38","v39","s40","s41","s42","s43") \
  QB("v40","v41","v42","v43","s44","s45","s46","s47") \
  QB("v44","v45","v46","v47","s48","s49","s50","s51") \
  QB("v48","v49","v50","v51","s52","s53","s54","s55") \
  QB("v52","v53","v54","v55","s56","s57","s58","s59") \
  QB("v56","v57","v58","v59","s60","s61","s62","s63") \
  QB("v60","v61","v62","v63","s64","s65","s66","s67")
#define QB_B \
  QB("v64","v65","v66","v67","s68","s69","s70","s71") \
  QB("v68","v69","v70","v71","s72","s73","s74","s75") \
  QB("v72","v73","v74","v75","s76","s77","s78","s79") \
  QB("v76","v77","v78","v79","s80","s81","s82","s83") \
  QB("v80","v81","v82","v83","s84","s85","s86","s87") \
  QB("v84","v85","v86","v87","s88","s89","s90","s91") \
  QB("v88","v89","v90","v91","s92","s93","s94","s95") \
  QB("v92","v93","v94","v95","s96","s97","s98","s99")

// Kernel 2 v6: split the 32B/q broadcast across the two cheap paths.
// Measured costs (r4/r5 busy-cycle accounting): uniform VMEM dwordx4 ~18cy/CU
// (64-lane writeback replication) -> never again; SMEM ~0.026 lines/cy/CU
// supply ceiling (r4 was exactly line-bound: 7168 lines -> 115us); LDS uniform
// ds_read_b128 <= ~12cy/CU.  So:
//   P (16B/q): block stages object o's P-stream in 32KB LDS, uniform
//              ds_read_b128 into double-banked VGPR halves v[32:63]/v[64:95]
//   N (16B/q): SMEM double-banked s[36:67]/s[68:99], 2 s_load_dwordx16 per
//              8q group  ->  128 lines/wave = 3584 lines/CU ~= 57us < 66us
//              compute floor
// One full lgkmcnt(0) per 8q group (SMEM completes OOO -> counted waits
// unsafe; full drains at 352cy spacing cover both ~300cy SMEM and ~120cy DS).
// Body stays the pinned 22-VALU/q QB network (bit-identical numerics).
// LDS 32KB + 768B overrun pad, MRG aliased -> 4 blocks/CU, 16 waves/CU.
__global__ void __launch_bounds__(TPB, 4) k_pairs(const float4* __restrict__ P4g,
                                                  const float4* __restrict__ N4g,
                                                  unsigned int* __restrict__ SD) {
    // P-stage during the scan; merge buffer [NW][PC][11] aliased afterwards.
    // +768B pad absorbs the final iteration's dangling ds prefetch (wu=3).
    __shared__ __align__(16) unsigned char shraw[N_PTS * sizeof(float4) + 768];
    float4* Pq = (float4*)shraw;
    float (*MRG)[PC][KNN + 1] = (float (*)[PC][KNN + 1])shraw;

    int bx   = blockIdx.x;
    int pair = bx >> 5;            // / NCHUNK
    int c64  = bx & (NCHUNK - 1);
    int b  = pair / 7;
    int oi = pair % 7;
    int o  = oi + (oi >= b ? 1 : 0);
    int tid  = threadIdx.x;
    int lane = tid & 63;
    int wu   = __builtin_amdgcn_readfirstlane(tid >> 6);
    int p    = c64 * PC + lane;

    // stage object o's P-stream (coalesced dwordx4 -> ds_write_b128)
    for (int i = tid; i < N_PTS; i += TPB) Pq[i] = P4g[o * N_PTS + i];

    float4 xp = P4g[b * N_PTS + p];          // per-lane point p (VMEM)
    float mx = -2.0f * xp.x, my = -2.0f * xp.y, mz = -2.0f * xp.z;
    float gx = -xp.x, gy = -xp.y, gz = -xp.z;

    const float4* No = N4g + o * N_PTS + wu * QC;   // uniform N base
    unsigned long long an = (unsigned long long)(uintptr_t)No;
    unsigned int bnl = (unsigned int)an, bnh = (unsigned int)(an >> 32);
    // raw LDS byte offset of this wave's P window (generic LDS addr: low 32
    // bits are the LDS offset on AMDGPU)
    unsigned int lb = (unsigned int)(uintptr_t)(&Pq[wu * QC]);

    const float FMAXE = __uint_as_float(0x7F7FFFFEu);   // FLT_MAX, LSB clear
    float d0_ = FMAXE, d1_ = FMAXE, d2_ = FMAXE, d3_ = FMAXE, d4_ = FMAXE;
    float d5_ = FMAXE, d6_ = FMAXE, d7_ = FMAXE, d8_ = FMAXE, d9_ = FMAXE;
    float t0, t1;

    __syncthreads();               // P staged before any ds_read

    asm volatile(
        "s_mov_b32 s32, %[bnl]\n"
        "s_mov_b32 s33, %[bnh]\n"
        // prologue: group 0 -> bank/half A
        "s_load_dwordx16 s[36:51], s[32:33], 0x0\n"
        "s_load_dwordx16 s[52:67], s[32:33], 0x40\n"
        DSA("0","16","32","48","64","80","96","112")
        "s_mov_b32 s30, 0\n"
        "Lkp%=:\n"
        "s_waitcnt lgkmcnt(0)\n"                         // A ready
        // prefetch group 2k+1 -> B
        "s_load_dwordx16 s[68:83], s[32:33], 0x80\n"
        "s_load_dwordx16 s[84:99], s[32:33], 0xc0\n"
        DSB("128","144","160","176","192","208","224","240")
        QB_A
        "s_waitcnt lgkmcnt(0)\n"                         // B ready
        // prefetch group 2k+2 -> A
        "s_load_dwordx16 s[36:51], s[32:33], 0x100\n"
        "s_load_dwordx16 s[52:67], s[32:33], 0x140\n"
        DSA("256","272","288","304","320","336","352","368")
        QB_B
        "s_add_u32 s32, s32, 0x100\n"
        "s_addc_u32 s33, s33, 0\n"
        "v_add_u32 %[lb], 256, %[lb]\n"
        "s_add_u32 s30, s30, 1\n"
        "s_cmp_lt_u32 s30, 32\n"
        "s_cbranch_scc1 Lkp%=\n"
        "s_waitcnt lgkmcnt(0)\n"   // drain dangling prefetch before reg reuse
        : [d0]"+v"(d0_), [d1]"+v"(d1_), [d2]"+v"(d2_), [d3]"+v"(d3_),
          [d4]"+v"(d4_), [d5]"+v"(d5_), [d6]"+v"(d6_), [d7]"+v"(d7_),
          [d8]"+v"(d8_), [d9]"+v"(d9_), [t0]"=&v"(t0), [t1]"=&v"(t1),
          [lb]"+v"(lb)
        : [mx]"v"(mx), [my]"v"(my), [mz]"v"(mz),
          [gx]"v"(gx), [gy]"v"(gy), [gz]"v"(gz),
          [bnl]"s"(bnl), [bnh]"s"(bnh)
        : "s30","s32","s33","s36","s37","s38","s39",
          "s40","s41","s42","s43","s44","s45","s46","s47","s48","s49",
          "s50","s51","s52","s53","s54","s55","s56","s57","s58","s59",
          "s60","s61","s62","s63","s64","s65","s66","s67","s68","s69",
          "s70","s71","s72","s73","s74","s75","s76","s77","s78","s79",
          "s80","s81","s82","s83","s84","s85","s86","s87","s88","s89",
          "s90","s91","s92","s93","s94","s95","s96","s97","s98","s99",
          "v32","v33","v34","v35","v36","v37","v38","v39",
          "v40","v41","v42","v43","v44","v45","v46","v47",
          "v48","v49","v50","v51","v52","v53","v54","v55",
          "v56","v57","v58","v59","v60","v61","v62","v63",
          "v64","v65","v66","v67","v68","v69","v70","v71",
          "v72","v73","v74","v75","v76","v77","v78","v79",
          "v80","v81","v82","v83","v84","v85","v86","v87",
          "v88","v89","v90","v91","v92","v93","v94","v95",
          "scc","vcc","memory");

    float td[KNN] = {d0_, d1_, d2_, d3_, d4_, d5_, d6_, d7_, d8_, d9_};

    __syncthreads();               // all ds_reads done; safe to alias MRG
    if (wu > 0) {
#pragma unroll
        for (int j = 0; j < KNN; j++) MRG[wu][lane][j] = td[j];
    }
    __syncthreads();

    if (wu == 0) {
        // merge the 3 foreign partial top-10 lists into this wave's network
        // (top-k selection is partition-invariant on the value multiset)
#pragma unroll
        for (int ww = 1; ww < NW; ww++) {
#pragma unroll
            for (int j = 0; j < KNN; j++) {
                float cp = MRG[ww][lane][j];
#pragma unroll
                for (int t = KNN - 1; t >= 1; --t)
                    td[t] = __builtin_amdgcn_fmed3f(td[t - 1], td[t], cp);
                td[0] = fminf(td[0], cp);
            }
        }

        int cnt = 0;
#pragma unroll
        for (int j = 0; j < KNN; j++) cnt += (int)(__float_as_uint(td[j]) & 1u);
        float d2 = __uint_as_float(__float_as_uint(td[0]) & 0xFFFFFFFEu) + xp.w;
        float d0 = sqrtf(fmaxf(d2, 0.0f));
        if (cnt > 8) d0 = -d0;           // sum(insides) > k*0.8 = 8  ->  >= 9
        atomicMin(&SD[b * N_PTS + p], enc_f(d0));
    }
}

// Kernel 3: decode and emit both outputs (signed_distance, then intersects
// as 0.0/1.0 floats).
__global__ void k_final(const unsigned int* __restrict__ SD,
                       float* __restrict__ out) {
    int gid = blockIdx.x * blockDim.x + threadIdx.x;
    if (gid >= N_OBJ * N_PTS) return;
    float sd = dec_f(SD[gid]);
    out[gid] = sd;
    out[N_OBJ * N_PTS + gid] = (sd < -TOLC) ? 1.0f : 0.0f;
}

extern "C" void kernel_launch(void* const* d_in, const int* in_sizes, int n_in,
                              void* d_out, int out_size, void* d_ws, size_t ws_size,
                              hipStream_t stream) {
    const float* pts     = (const float*)d_in[0];   // (8,2048,6)
    const float* T_est   = (const float*)d_in[1];   // (8,4,4)
    const float* T_plane = (const float*)d_in[2];   // (4,4)
    // d_in[3] is k == 10, hardcoded as KNN

    // workspace layout: P4 (256KB) | N4 (256KB) | SD (64KB)
    float4*       P4 = (float4*)d_ws;
    float4*       N4 = P4 + N_OBJ * N_PTS;
    unsigned int* SD = (unsigned int*)(N4 + N_OBJ * N_PTS);

    float* out = (float*)d_out;

    k_transform<<<(N_OBJ * N_PTS) / 256, 256, 0, stream>>>(pts, T_est, T_plane, P4, N4, SD);
    k_pairs<<<N_OBJ * (N_OBJ - 1) * NCHUNK, TPB, 0, stream>>>(P4, N4, SD);
    k_final<<<(N_OBJ * N_PTS) / 256, 256, 0, stream>>>(SD, out);
}